// Round 4
// baseline (158.661 us; speedup 1.0000x reference)
//
#include <hip/hip_runtime.h>
#include <hip/hip_bf16.h>

typedef __bf16 bf16_t;
typedef bf16_t bf16x8 __attribute__((ext_vector_type(8)));
typedef bf16_t bf16x4 __attribute__((ext_vector_type(4)));
typedef float f32x4 __attribute__((ext_vector_type(4)));
typedef unsigned int u32;

#define NB 4
#define SS 4096
#define DM 768
#define DH 64
#define NROW (NB * SS)   // 16384
#define WV 8
#define CSCALE (0.125f * 1.44269504088896341f)   // 1/sqrt(64) * log2(e)

// ws byte offsets
#define QOFF 0u
#define KOFF 2097152u
#define VOFF 4194304u
#define WOFF 6291456u
#define FOFF 6586368u          // flags: 512 * 4 B
#define POFF 6590464u          // partials: 1024 * 8448 B
#define PART_F32 2112          // 2048 O + 64 ml (f32 elements per partial)
#define WS_NEED (POFF + 1024ull * 8448ull)

// ---------------------------------------------------------------------------
// Kernel 1: transpose W_{Q,K,V} [768][64] fp32 -> Wt[3][64][768] bf16
// ---------------------------------------------------------------------------
__global__ __launch_bounds__(256) void wt_kernel(const float* __restrict__ wq,
                                                 const float* __restrict__ wk,
                                                 const float* __restrict__ wv,
                                                 bf16_t* __restrict__ wt) {
    int id = blockIdx.x * 256 + threadIdx.x;
    if (id >= 3 * DM * DH) return;
    int m = id / (DM * DH);
    int r = id - m * (DM * DH);
    int k = r >> 6;
    int c = r & 63;
    const float* w = (m == 0) ? wq : (m == 1) ? wk : wv;
    wt[(size_t)m * DH * DM + (size_t)c * DM + k] = (bf16_t)w[k * DH + c];
}

// ---------------------------------------------------------------------------
// Kernel 2: projections, software-pipelined. 1024 blocks x 4 waves; wave =
// 16 rows x 48 cols. x A-fragments for step k+1 prefetched into registers
// during step k; all 6 B-frags loaded before the 6 MFMAs of a step.
// ---------------------------------------------------------------------------
__global__ __launch_bounds__(256, 4) void proj_kernel(const float* __restrict__ x,
                                                      const bf16_t* __restrict__ wt,
                                                      bf16_t* __restrict__ Qo,
                                                      bf16_t* __restrict__ Ko,
                                                      bf16_t* __restrict__ Vt) {
    const int lane = threadIdx.x & 63;
    const int wid = threadIdx.x >> 6;
    const int l15 = lane & 15;
    const int g = lane >> 4;
    const int m0 = blockIdx.x * 16;

    f32x4 acc[3];
    #pragma unroll
    for (int n = 0; n < 3; n++)
        #pragma unroll
        for (int j = 0; j < 4; j++) acc[n][j] = 0.0f;

    const float* xrow = x + (size_t)(m0 + l15) * DM + g * 8;

    f32x4 ax[2][2];   // current step's raw fp32 x fragments [kk][half]
    #pragma unroll
    for (int kk = 0; kk < 2; kk++) {
        ax[kk][0] = *reinterpret_cast<const f32x4*>(xrow + kk * 32);
        ax[kk][1] = *reinterpret_cast<const f32x4*>(xrow + kk * 32 + 4);
    }

    #pragma unroll
    for (int k0 = 0; k0 < DM; k0 += 64) {
        f32x4 axn[2][2];
        if (k0 + 64 < DM) {
            #pragma unroll
            for (int kk = 0; kk < 2; kk++) {
                axn[kk][0] = *reinterpret_cast<const f32x4*>(xrow + k0 + 64 + kk * 32);
                axn[kk][1] = *reinterpret_cast<const f32x4*>(xrow + k0 + 64 + kk * 32 + 4);
            }
        }
        // convert current A to bf16
        bf16x8 a[2];
        #pragma unroll
        for (int kk = 0; kk < 2; kk++) {
            bf16x8 t;
            #pragma unroll
            for (int j = 0; j < 4; j++) { t[j] = (bf16_t)ax[kk][0][j]; t[4 + j] = (bf16_t)ax[kk][1][j]; }
            a[kk] = t;
        }
        // load all 6 B fragments, then MFMA
        bf16x8 bb[3][2];
        #pragma unroll
        for (int n = 0; n < 3; n++) {
            const int gn = wid * 3 + n;
            const int m = gn >> 2;
            const int cj = gn & 3;
            #pragma unroll
            for (int kk = 0; kk < 2; kk++)
                bb[n][kk] = *reinterpret_cast<const bf16x8*>(
                    wt + (size_t)m * DH * DM + (size_t)(cj * 16 + l15) * DM + k0 + kk * 32 + g * 8);
        }
        #pragma unroll
        for (int n = 0; n < 3; n++)
            #pragma unroll
            for (int kk = 0; kk < 2; kk++)
                acc[n] = __builtin_amdgcn_mfma_f32_16x16x32_bf16(a[kk], bb[n][kk], acc[n], 0, 0, 0);

        if (k0 + 64 < DM) {
            #pragma unroll
            for (int kk = 0; kk < 2; kk++) { ax[kk][0] = axn[kk][0]; ax[kk][1] = axn[kk][1]; }
        }
    }

    #pragma unroll
    for (int n = 0; n < 3; n++) {
        const int gn = wid * 3 + n;
        const int m = gn >> 2;
        const int cj = gn & 3;
        #pragma unroll
        for (int j = 0; j < 4; j++) {
            int row = m0 + g * 4 + j;
            int col = cj * 16 + l15;
            float v = acc[n][j];
            if (m == 0)      Qo[(size_t)row * DH + col] = (bf16_t)(v * CSCALE);
            else if (m == 1) Ko[(size_t)row * DH + col] = (bf16_t)v;
            else             Vt[(size_t)col * NROW + row] = (bf16_t)v;
        }
    }
}

// ---------------------------------------------------------------------------
// Kernel 3: flash attention, swapped-operand, kv-split 8 waves/block.
// SPLIT=true: 1024 blocks = (b, tile, half); each half covers kv parity class
// h via consumer id c = h*8+w, stride 16. Partial (m,l,O) -> ws; second
// finisher (device-scope flag) merges & writes output (symmetric => exact).
// SPLIT=false: R3 single-block-per-tile fallback (ws too small for partials).
// ---------------------------------------------------------------------------
template<bool SPLIT>
__global__ __launch_bounds__(512, 2) void attn_kernel(const bf16_t* __restrict__ Q,
                                                      const bf16_t* __restrict__ K,
                                                      const bf16_t* __restrict__ Vt,
                                                      float* __restrict__ out,
                                                      float* __restrict__ part,
                                                      int* __restrict__ flags) {
    __shared__ __align__(16) float Ob[4][2][4][4][16][4];
    __shared__ float Ml[4][2][2][16];

    const int tid = threadIdx.x;
    const int lane = tid & 63;
    const int w = tid >> 6;
    const int l15 = lane & 15;
    const int g = lane >> 4;
    const int bx = blockIdx.x;
    const int b = bx & 3;
    int tile, h;
    if (SPLIT) { int r = bx >> 2; h = r & 1; tile = 127 - (r >> 1); }
    else       { h = 0; tile = 127 - (bx >> 2); }
    const int q0 = tile * 32;

    const bf16_t* Qb = Q + (size_t)b * SS * DH;
    const bf16_t* Kb = K + (size_t)b * SS * DH;

    bf16x8 aq[2][2];
    #pragma unroll
    for (int fi = 0; fi < 2; fi++)
        #pragma unroll
        for (int kk = 0; kk < 2; kk++)
            aq[fi][kk] = *reinterpret_cast<const bf16x8*>(
                Qb + (size_t)(q0 + fi * 16 + l15) * DH + kk * 32 + g * 8);

    f32x4 o[2][4];
    float m_[2] = {-1e30f, -1e30f};
    float l_[2] = {0.0f, 0.0f};
    #pragma unroll
    for (int fi = 0; fi < 2; fi++)
        #pragma unroll
        for (int cjd = 0; cjd < 4; cjd++)
            #pragma unroll
            for (int j = 0; j < 4; j++) o[fi][cjd][j] = 0.0f;

    const int nkv = (tile >> 1) + 1;
    const int c0 = SPLIT ? (h * 8 + w) : w;
    const int cstride = SPLIT ? 16 : 8;

    for (int kt = c0; kt < nkv; kt += cstride) {
        const int kv0 = kt * 64;

        // S^T = K Q^T
        f32x4 s[2][4];
        #pragma unroll
        for (int fi = 0; fi < 2; fi++)
            #pragma unroll
            for (int cj = 0; cj < 4; cj++)
                #pragma unroll
                for (int j = 0; j < 4; j++) s[fi][cj][j] = 0.0f;
        #pragma unroll
        for (int cj = 0; cj < 4; cj++) {
            #pragma unroll
            for (int kk = 0; kk < 2; kk++) {
                bf16x8 kf = *reinterpret_cast<const bf16x8*>(
                    Kb + (size_t)(kv0 + cj * 16 + l15) * DH + kk * 32 + g * 8);
                #pragma unroll
                for (int fi = 0; fi < 2; fi++)
                    s[fi][cj] = __builtin_amdgcn_mfma_f32_16x16x32_bf16(kf, aq[fi][kk], s[fi][cj], 0, 0, 0);
            }
        }

        // V fragments issued now: latency hides under softmax
        bf16x8 vf[4][2];
        #pragma unroll
        for (int cjd = 0; cjd < 4; cjd++)
            #pragma unroll
            for (int kkc = 0; kkc < 2; kkc++)
                vf[cjd][kkc] = *reinterpret_cast<const bf16x8*>(
                    Vt + (size_t)(cjd * 16 + l15) * NROW + (size_t)b * SS + kv0 + kkc * 32 + g * 8);

        // causal mask only on diagonal tiles
        if (kv0 + 63 > q0) {
            #pragma unroll
            for (int fi = 0; fi < 2; fi++) {
                const int q = q0 + fi * 16 + l15;
                #pragma unroll
                for (int cj = 0; cj < 4; cj++) {
                    const int kvb = kv0 + cj * 16 + g * 4;
                    #pragma unroll
                    for (int j = 0; j < 4; j++)
                        if (kvb + j > q) s[fi][cj][j] = -1e30f;
                }
            }
        }

        u32 pb[2][4][2];
        float fac[2];
        #pragma unroll
        for (int fi = 0; fi < 2; fi++) {
            float c0m = fmaxf(fmaxf(s[fi][0][0], s[fi][0][1]), fmaxf(s[fi][0][2], s[fi][0][3]));
            float c1m = fmaxf(fmaxf(s[fi][1][0], s[fi][1][1]), fmaxf(s[fi][1][2], s[fi][1][3]));
            float c2m = fmaxf(fmaxf(s[fi][2][0], s[fi][2][1]), fmaxf(s[fi][2][2], s[fi][2][3]));
            float c3m = fmaxf(fmaxf(s[fi][3][0], s[fi][3][1]), fmaxf(s[fi][3][2], s[fi][3][3]));
            float mx = fmaxf(fmaxf(c0m, c1m), fmaxf(c2m, c3m));
            mx = fmaxf(mx, __shfl_xor(mx, 16));
            mx = fmaxf(mx, __shfl_xor(mx, 32));
            float mn = fmaxf(m_[fi], mx);
            fac[fi] = exp2f(m_[fi] - mn);
            m_[fi] = mn;

            #pragma unroll
            for (int cj = 0; cj < 4; cj++)
                #pragma unroll
                for (int j = 0; j < 4; j++)
                    s[fi][cj][j] = exp2f(s[fi][cj][j] - mn);

            float t0 = (s[fi][0][0] + s[fi][0][1]) + (s[fi][0][2] + s[fi][0][3]);
            float t1 = (s[fi][1][0] + s[fi][1][1]) + (s[fi][1][2] + s[fi][1][3]);
            float t2 = (s[fi][2][0] + s[fi][2][1]) + (s[fi][2][2] + s[fi][2][3]);
            float t3 = (s[fi][3][0] + s[fi][3][1]) + (s[fi][3][2] + s[fi][3][3]);
            float sum = (t0 + t1) + (t2 + t3);
            sum += __shfl_xor(sum, 16);
            sum += __shfl_xor(sum, 32);
            l_[fi] = l_[fi] * fac[fi] + sum;

            #pragma unroll
            for (int cj = 0; cj < 4; cj++) {
                union { u32 w2[2]; bf16x4 v; } pu;
                #pragma unroll
                for (int j = 0; j < 4; j++) pu.v[j] = (bf16_t)s[fi][cj][j];
                pb[fi][cj][0] = pu.w2[0];
                pb[fi][cj][1] = pu.w2[1];
            }
        }

        #pragma unroll
        for (int fi = 0; fi < 2; fi++)
            #pragma unroll
            for (int cjd = 0; cjd < 4; cjd++)
                #pragma unroll
                for (int j = 0; j < 4; j++) o[fi][cjd][j] *= fac[fi];

        // PV: O^T += V^T P^T
        const int srcA = l15 + ((lane >> 4) & 1) * 32;
        const int srcB = srcA + 16;
        const bool hicj = (lane >= 32);
        #pragma unroll
        for (int kkc = 0; kkc < 2; kkc++) {
            bf16x8 pf[2];
            #pragma unroll
            for (int fi = 0; fi < 2; fi++) {
                u32 a00 = (u32)__shfl((int)pb[fi][2 * kkc + 0][0], srcA);
                u32 a01 = (u32)__shfl((int)pb[fi][2 * kkc + 0][1], srcA);
                u32 a10 = (u32)__shfl((int)pb[fi][2 * kkc + 1][0], srcA);
                u32 a11 = (u32)__shfl((int)pb[fi][2 * kkc + 1][1], srcA);
                u32 b00 = (u32)__shfl((int)pb[fi][2 * kkc + 0][0], srcB);
                u32 b01 = (u32)__shfl((int)pb[fi][2 * kkc + 0][1], srcB);
                u32 b10 = (u32)__shfl((int)pb[fi][2 * kkc + 1][0], srcB);
                u32 b11 = (u32)__shfl((int)pb[fi][2 * kkc + 1][1], srcB);
                union { u32 w4[4]; bf16x8 v; } uu;
                uu.w4[0] = hicj ? a10 : a00;
                uu.w4[1] = hicj ? a11 : a01;
                uu.w4[2] = hicj ? b10 : b00;
                uu.w4[3] = hicj ? b11 : b01;
                pf[fi] = uu.v;
            }
            #pragma unroll
            for (int cjd = 0; cjd < 4; cjd++)
                #pragma unroll
                for (int fi = 0; fi < 2; fi++)
                    o[fi][cjd] = __builtin_amdgcn_mfma_f32_16x16x32_bf16(vf[cjd][kkc], pf[fi], o[fi][cjd], 0, 0, 0);
        }
    }

    // ---- intra-block tree combine (4,2,1) ----
    #pragma unroll
    for (int r = WV / 2; r >= 1; r >>= 1) {
        if (w >= r && w < 2 * r) {
            const int s_ = w - r;
            #pragma unroll
            for (int fi = 0; fi < 2; fi++)
                #pragma unroll
                for (int cjd = 0; cjd < 4; cjd++)
                    *reinterpret_cast<f32x4*>(&Ob[s_][fi][cjd][g][l15][0]) = o[fi][cjd];
            if (lane < 16) {
                #pragma unroll
                for (int fi = 0; fi < 2; fi++) {
                    Ml[s_][fi][0][l15] = m_[fi];
                    Ml[s_][fi][1][l15] = l_[fi];
                }
            }
        }
        __syncthreads();
        if (w < r) {
            #pragma unroll
            for (int fi = 0; fi < 2; fi++) {
                float mb = Ml[w][fi][0][l15];
                float lb = Ml[w][fi][1][l15];
                float M = fmaxf(m_[fi], mb);
                float fa = exp2f(m_[fi] - M);
                float fb = exp2f(mb - M);
                l_[fi] = l_[fi] * fa + lb * fb;
                m_[fi] = M;
                #pragma unroll
                for (int cjd = 0; cjd < 4; cjd++) {
                    f32x4 ov = *reinterpret_cast<const f32x4*>(&Ob[w][fi][cjd][g][l15][0]);
                    o[fi][cjd] = o[fi][cjd] * fa + ov * fb;
                }
            }
        }
        __syncthreads();
    }

    if (w != 0) return;

    if (!SPLIT) {
        float* ob = out + ((size_t)b * SS + q0) * DH;
        #pragma unroll
        for (int fi = 0; fi < 2; fi++) {
            float rl = 1.0f / l_[fi];
            #pragma unroll
            for (int cjd = 0; cjd < 4; cjd++) {
                f32x4 v = o[fi][cjd] * rl;
                *reinterpret_cast<f32x4*>(&ob[(size_t)(fi * 16 + l15) * DH + cjd * 16 + g * 4]) = v;
            }
        }
        return;
    }

    // ---- SPLIT: write partial, flag, second finisher merges ----
    const int fid = b * 128 + tile;
    const int pid = fid * 2 + h;
    float* P = part + (size_t)pid * PART_F32;
    #pragma unroll
    for (int fi = 0; fi < 2; fi++)
        #pragma unroll
        for (int cjd = 0; cjd < 4; cjd++)
            *reinterpret_cast<f32x4*>(P + (((fi * 4 + cjd) * 4 + g) * 16 + l15) * 4) = o[fi][cjd];
    if (g == 0) {
        #pragma unroll
        for (int fi = 0; fi < 2; fi++) {
            P[2048 + fi * 32 + l15] = m_[fi];
            P[2048 + fi * 32 + 16 + l15] = l_[fi];
        }
    }
    __threadfence();
    int old = 0;
    if (lane == 0) old = atomicAdd(&flags[fid], 1);
    old = __shfl(old, 0);
    if (old != 1) return;
    __threadfence();

    const float* Po = part + (size_t)(pid ^ 1) * PART_F32;
    float* ob = out + ((size_t)b * SS + q0) * DH;
    #pragma unroll
    for (int fi = 0; fi < 2; fi++) {
        float mo = Po[2048 + fi * 32 + l15];
        float lo = Po[2048 + fi * 32 + 16 + l15];
        float M = fmaxf(m_[fi], mo);
        float fa = exp2f(m_[fi] - M);
        float fb = exp2f(mo - M);
        float L = l_[fi] * fa + lo * fb;
        float rl = 1.0f / L;
        #pragma unroll
        for (int cjd = 0; cjd < 4; cjd++) {
            f32x4 ov = *reinterpret_cast<const f32x4*>(Po + (((fi * 4 + cjd) * 4 + g) * 16 + l15) * 4);
            f32x4 res = (o[fi][cjd] * fa + ov * fb) * rl;
            *reinterpret_cast<f32x4*>(&ob[(size_t)(fi * 16 + l15) * DH + cjd * 16 + g * 4]) = res;
        }
    }
}

// ---------------------------------------------------------------------------
extern "C" void kernel_launch(void* const* d_in, const int* in_sizes, int n_in,
                              void* d_out, int out_size, void* d_ws, size_t ws_size,
                              hipStream_t stream) {
    const float* x  = (const float*)d_in[0];
    const float* wq = (const float*)d_in[1];
    const float* wk = (const float*)d_in[2];
    const float* wv = (const float*)d_in[3];
    float* out = (float*)d_out;

    char* ws = (char*)d_ws;
    bf16_t* Qw = (bf16_t*)(ws + QOFF);
    bf16_t* Kw = (bf16_t*)(ws + KOFF);
    bf16_t* Vt = (bf16_t*)(ws + VOFF);
    bf16_t* Wt = (bf16_t*)(ws + WOFF);
    int*    flags = (int*)(ws + FOFF);
    float*  part  = (float*)(ws + POFF);

    hipLaunchKernelGGL(wt_kernel, dim3((3 * DM * DH + 255) / 256), dim3(256), 0, stream,
                       wq, wk, wv, Wt);
    hipLaunchKernelGGL(proj_kernel, dim3(NROW / 16), dim3(256), 0, stream,
                       x, Wt, Qw, Kw, Vt);

    if (ws_size >= WS_NEED) {
        hipMemsetAsync(flags, 0, 512 * sizeof(int), stream);
        hipLaunchKernelGGL((attn_kernel<true>), dim3(NB * 128 * 2), dim3(512), 0, stream,
                           Qw, Kw, Vt, out, part, flags);
    } else {
        hipLaunchKernelGGL((attn_kernel<false>), dim3(NB * 128), dim3(512), 0, stream,
                           Qw, Kw, Vt, out, part, flags);
    }
}

// Round 5
// 110.691 us; speedup vs baseline: 1.4334x; 1.4334x over previous
//
#include <hip/hip_runtime.h>
#include <hip/hip_bf16.h>

typedef __bf16 bf16_t;
typedef bf16_t bf16x8 __attribute__((ext_vector_type(8)));
typedef bf16_t bf16x4 __attribute__((ext_vector_type(4)));
typedef float f32x4 __attribute__((ext_vector_type(4)));
typedef unsigned int u32;

#define NB 4
#define SS 4096
#define DM 768
#define DH 64
#define NROW (NB * SS)   // 16384
#define CSCALE (0.125f * 1.44269504088896341f)   // 1/sqrt(64) * log2(e)

// ws byte offsets
#define QOFF 0u
#define KOFF 2097152u
#define VOFF 4194304u
#define WOFF 6291456u

// ---------------------------------------------------------------------------
// Kernel 1: transpose W_{Q,K,V} [768][64] fp32 -> Wt[3][64][768] bf16
// ---------------------------------------------------------------------------
__global__ __launch_bounds__(256) void wt_kernel(const float* __restrict__ wq,
                                                 const float* __restrict__ wk,
                                                 const float* __restrict__ wv,
                                                 bf16_t* __restrict__ wt) {
    int id = blockIdx.x * 256 + threadIdx.x;
    if (id >= 3 * DM * DH) return;
    int m = id / (DM * DH);
    int r = id - m * (DM * DH);
    int k = r >> 6;
    int c = r & 63;
    const float* w = (m == 0) ? wq : (m == 1) ? wk : wv;
    wt[(size_t)m * DH * DM + (size_t)c * DM + k] = (bf16_t)w[k * DH + c];
}

// ---------------------------------------------------------------------------
// Kernel 2: projections. 512 blocks x 4 waves; wave = 32 rows x 48 cols.
// Deep prefetch: x 2 steps ahead (16 f32x4 in flight), Wt 1 step ahead.
// launch_bounds(256,2): ~165 VGPR ok, grid caps occupancy at 2 waves/SIMD
// anyway -- bet on per-wave memory-level parallelism.
// ---------------------------------------------------------------------------
__global__ __launch_bounds__(256, 2) void proj_kernel(const float* __restrict__ x,
                                                      const bf16_t* __restrict__ wt,
                                                      bf16_t* __restrict__ Qo,
                                                      bf16_t* __restrict__ Ko,
                                                      bf16_t* __restrict__ Vt) {
    const int lane = threadIdx.x & 63;
    const int wid = threadIdx.x >> 6;
    const int l15 = lane & 15;
    const int g = lane >> 4;
    const int m0 = blockIdx.x * 32;

    f32x4 acc[2][3];
    #pragma unroll
    for (int fi = 0; fi < 2; fi++)
        #pragma unroll
        for (int n = 0; n < 3; n++)
            #pragma unroll
            for (int j = 0; j < 4; j++) acc[fi][n][j] = 0.0f;

    const float* xb = x + (size_t)(m0 + l15) * DM + g * 8;

    size_t wbase[3];
    #pragma unroll
    for (int n = 0; n < 3; n++) {
        const int gn = wid * 3 + n;
        const int mm = gn >> 2;
        const int cj = gn & 3;
        wbase[n] = (size_t)mm * DH * DM + (size_t)(cj * 16 + l15) * DM + g * 8;
    }

    f32x4 pf[2][2][2][2];   // [slot][fi][kk][half]
    #pragma unroll
    for (int s = 0; s < 2; s++)
        #pragma unroll
        for (int fi = 0; fi < 2; fi++)
            #pragma unroll
            for (int kk = 0; kk < 2; kk++)
                #pragma unroll
                for (int h = 0; h < 2; h++)
                    pf[s][fi][kk][h] = *reinterpret_cast<const f32x4*>(
                        xb + (size_t)fi * 16 * DM + s * 64 + kk * 32 + h * 4);

    bf16x8 bb[2][3][2];
    #pragma unroll
    for (int n = 0; n < 3; n++)
        #pragma unroll
        for (int kk = 0; kk < 2; kk++)
            bb[0][n][kk] = *reinterpret_cast<const bf16x8*>(wt + wbase[n] + kk * 32);

    #pragma unroll
    for (int k = 0; k < 12; k++) {
        const int cur = k & 1;
        const int nxt = (k + 1) & 1;
        // consume current x slot
        bf16x8 a[2][2];
        #pragma unroll
        for (int fi = 0; fi < 2; fi++)
            #pragma unroll
            for (int kk = 0; kk < 2; kk++) {
                bf16x8 t;
                #pragma unroll
                for (int j = 0; j < 4; j++) {
                    t[j] = (bf16_t)pf[cur][fi][kk][0][j];
                    t[4 + j] = (bf16_t)pf[cur][fi][kk][1][j];
                }
                a[fi][kk] = t;
            }
        // issue x loads for step k+2 into the freed slot
        if (k + 2 < 12) {
            #pragma unroll
            for (int fi = 0; fi < 2; fi++)
                #pragma unroll
                for (int kk = 0; kk < 2; kk++)
                    #pragma unroll
                    for (int h = 0; h < 2; h++)
                        pf[cur][fi][kk][h] = *reinterpret_cast<const f32x4*>(
                            xb + (size_t)fi * 16 * DM + (k + 2) * 64 + kk * 32 + h * 4);
        }
        // issue Wt loads for step k+1
        if (k + 1 < 12) {
            #pragma unroll
            for (int n = 0; n < 3; n++)
                #pragma unroll
                for (int kk = 0; kk < 2; kk++)
                    bb[nxt][n][kk] = *reinterpret_cast<const bf16x8*>(
                        wt + wbase[n] + (k + 1) * 64 + kk * 32);
        }
        // MFMA
        #pragma unroll
        for (int n = 0; n < 3; n++)
            #pragma unroll
            for (int kk = 0; kk < 2; kk++)
                #pragma unroll
                for (int fi = 0; fi < 2; fi++)
                    acc[fi][n] = __builtin_amdgcn_mfma_f32_16x16x32_bf16(a[fi][kk], bb[cur][n][kk], acc[fi][n], 0, 0, 0);
    }

    #pragma unroll
    for (int n = 0; n < 3; n++) {
        const int gn = wid * 3 + n;
        const int mm = gn >> 2;
        const int cj = gn & 3;
        #pragma unroll
        for (int fi = 0; fi < 2; fi++)
            #pragma unroll
            for (int j = 0; j < 4; j++) {
                int row = m0 + fi * 16 + g * 4 + j;
                int col = cj * 16 + l15;
                float v = acc[fi][n][j];
                if (mm == 0)      Qo[(size_t)row * DH + col] = (bf16_t)(v * CSCALE);
                else if (mm == 1) Ko[(size_t)row * DH + col] = (bf16_t)v;
                else              Vt[(size_t)col * NROW + row] = (bf16_t)v;
            }
    }
}

// ---------------------------------------------------------------------------
// Kernel 3: flash attention. 256 UNIFORM blocks x 16 waves (1024 thr).
// Block = pair of q-tiles (tA = 64+pr big, tB = 63-pr small): nkvA+nkvB = 64/65
// constant -> zero load imbalance, all blocks resident (1/CU, 16 waves/CU).
// Each phase: kv-split x16 with per-wave online softmax (swapped-operand,
// in-register), then 16->1 combine through 4 LDS slots (two half-steps 16->8,
// then the proven 8->1 tree). XCD-pinned mapping keeps each batch's K/V on 2
// XCDs' L2.
// ---------------------------------------------------------------------------
__global__ __launch_bounds__(1024, 4) void attn_kernel(const bf16_t* __restrict__ Q,
                                                       const bf16_t* __restrict__ K,
                                                       const bf16_t* __restrict__ Vt,
                                                       float* __restrict__ out) {
    __shared__ __align__(16) float Ob[4][2][4][4][16][4];  // [slot][fi][cjd][g][l15][j]
    __shared__ float Ml[4][2][2][16];                      // [slot][fi][m/l][l15]

    const int tid = threadIdx.x;
    const int lane = tid & 63;
    const int w = tid >> 6;              // 0..15
    const int l15 = lane & 15;
    const int g = lane >> 4;
    const int bx = blockIdx.x;           // 0..255
    const int b = (bx & 7) >> 1;         // batch pinned to 2 XCDs
    const int pr = (bx >> 3) * 2 + (bx & 1);   // 0..63

    const bf16_t* Qb = Q + (size_t)b * SS * DH;
    const bf16_t* Kb = K + (size_t)b * SS * DH;

    #define WRITE_SLOT(s_)                                                          \
        {                                                                           \
            _Pragma("unroll")                                                       \
            for (int fi = 0; fi < 2; fi++)                                          \
                _Pragma("unroll")                                                   \
                for (int cjd = 0; cjd < 4; cjd++)                                   \
                    *reinterpret_cast<f32x4*>(&Ob[s_][fi][cjd][g][l15][0]) = o[fi][cjd]; \
            if (lane < 16) {                                                        \
                _Pragma("unroll")                                                   \
                for (int fi = 0; fi < 2; fi++) {                                    \
                    Ml[s_][fi][0][l15] = m_[fi];                                    \
                    Ml[s_][fi][1][l15] = l_[fi];                                    \
                }                                                                   \
            }                                                                       \
        }

    #define MERGE_SLOT(s_)                                                          \
        {                                                                           \
            _Pragma("unroll")                                                       \
            for (int fi = 0; fi < 2; fi++) {                                        \
                float mb = Ml[s_][fi][0][l15];                                      \
                float lb = Ml[s_][fi][1][l15];                                      \
                float M = fmaxf(m_[fi], mb);                                        \
                float fa = exp2f(m_[fi] - M);                                       \
                float fb = exp2f(mb - M);                                           \
                l_[fi] = l_[fi] * fa + lb * fb;                                     \
                m_[fi] = M;                                                         \
                _Pragma("unroll")                                                   \
                for (int cjd = 0; cjd < 4; cjd++) {                                 \
                    f32x4 ov = *reinterpret_cast<const f32x4*>(&Ob[s_][fi][cjd][g][l15][0]); \
                    o[fi][cjd] = o[fi][cjd] * fa + ov * fb;                         \
                }                                                                   \
            }                                                                       \
        }

    #pragma unroll
    for (int ph = 0; ph < 2; ph++) {
        const int tile = (ph == 0) ? (64 + pr) : (63 - pr);
        const int q0 = tile * 32;
        const int nkv = (tile >> 1) + 1;

        // Q fragments (pre-scaled by CSCALE at projection)
        bf16x8 aq[2][2];
        #pragma unroll
        for (int fi = 0; fi < 2; fi++)
            #pragma unroll
            for (int kk = 0; kk < 2; kk++)
                aq[fi][kk] = *reinterpret_cast<const bf16x8*>(
                    Qb + (size_t)(q0 + fi * 16 + l15) * DH + kk * 32 + g * 8);

        f32x4 o[2][4];
        float m_[2] = {-1e30f, -1e30f};
        float l_[2] = {0.0f, 0.0f};
        #pragma unroll
        for (int fi = 0; fi < 2; fi++)
            #pragma unroll
            for (int cjd = 0; cjd < 4; cjd++)
                #pragma unroll
                for (int j = 0; j < 4; j++) o[fi][cjd][j] = 0.0f;

        for (int kt = w; kt < nkv; kt += 16) {
            const int kv0 = kt * 64;

            // S^T = K Q^T : s[fi][cj] holds kv rows (g*4+j), q cols (l15)
            f32x4 s[2][4];
            #pragma unroll
            for (int fi = 0; fi < 2; fi++)
                #pragma unroll
                for (int cj = 0; cj < 4; cj++)
                    #pragma unroll
                    for (int j = 0; j < 4; j++) s[fi][cj][j] = 0.0f;
            #pragma unroll
            for (int cj = 0; cj < 4; cj++) {
                #pragma unroll
                for (int kk = 0; kk < 2; kk++) {
                    bf16x8 kf = *reinterpret_cast<const bf16x8*>(
                        Kb + (size_t)(kv0 + cj * 16 + l15) * DH + kk * 32 + g * 8);
                    #pragma unroll
                    for (int fi = 0; fi < 2; fi++)
                        s[fi][cj] = __builtin_amdgcn_mfma_f32_16x16x32_bf16(kf, aq[fi][kk], s[fi][cj], 0, 0, 0);
                }
            }

            // V fragments issued now: L2 latency hides under softmax
            bf16x8 vf[4][2];
            #pragma unroll
            for (int cjd = 0; cjd < 4; cjd++)
                #pragma unroll
                for (int kkc = 0; kkc < 2; kkc++)
                    vf[cjd][kkc] = *reinterpret_cast<const bf16x8*>(
                        Vt + (size_t)(cjd * 16 + l15) * NROW + (size_t)b * SS + kv0 + kkc * 32 + g * 8);

            // causal mask only on diagonal tiles
            if (kv0 + 63 > q0) {
                #pragma unroll
                for (int fi = 0; fi < 2; fi++) {
                    const int q = q0 + fi * 16 + l15;
                    #pragma unroll
                    for (int cj = 0; cj < 4; cj++) {
                        const int kvb = kv0 + cj * 16 + g * 4;
                        #pragma unroll
                        for (int j = 0; j < 4; j++)
                            if (kvb + j > q) s[fi][cj][j] = -1e30f;
                    }
                }
            }

            // per-fi online softmax: in-lane tree + shfl_xor(16,32)
            u32 pb[2][4][2];
            float fac[2];
            #pragma unroll
            for (int fi = 0; fi < 2; fi++) {
                float c0m = fmaxf(fmaxf(s[fi][0][0], s[fi][0][1]), fmaxf(s[fi][0][2], s[fi][0][3]));
                float c1m = fmaxf(fmaxf(s[fi][1][0], s[fi][1][1]), fmaxf(s[fi][1][2], s[fi][1][3]));
                float c2m = fmaxf(fmaxf(s[fi][2][0], s[fi][2][1]), fmaxf(s[fi][2][2], s[fi][2][3]));
                float c3m = fmaxf(fmaxf(s[fi][3][0], s[fi][3][1]), fmaxf(s[fi][3][2], s[fi][3][3]));
                float mx = fmaxf(fmaxf(c0m, c1m), fmaxf(c2m, c3m));
                mx = fmaxf(mx, __shfl_xor(mx, 16));
                mx = fmaxf(mx, __shfl_xor(mx, 32));
                float mn = fmaxf(m_[fi], mx);
                fac[fi] = exp2f(m_[fi] - mn);
                m_[fi] = mn;

                #pragma unroll
                for (int cj = 0; cj < 4; cj++)
                    #pragma unroll
                    for (int j = 0; j < 4; j++)
                        s[fi][cj][j] = exp2f(s[fi][cj][j] - mn);

                float t0 = (s[fi][0][0] + s[fi][0][1]) + (s[fi][0][2] + s[fi][0][3]);
                float t1 = (s[fi][1][0] + s[fi][1][1]) + (s[fi][1][2] + s[fi][1][3]);
                float t2 = (s[fi][2][0] + s[fi][2][1]) + (s[fi][2][2] + s[fi][2][3]);
                float t3 = (s[fi][3][0] + s[fi][3][1]) + (s[fi][3][2] + s[fi][3][3]);
                float sum = (t0 + t1) + (t2 + t3);
                sum += __shfl_xor(sum, 16);
                sum += __shfl_xor(sum, 32);
                l_[fi] = l_[fi] * fac[fi] + sum;

                #pragma unroll
                for (int cj = 0; cj < 4; cj++) {
                    union { u32 w2[2]; bf16x4 v; } pu;
                    #pragma unroll
                    for (int j = 0; j < 4; j++) pu.v[j] = (bf16_t)s[fi][cj][j];
                    pb[fi][cj][0] = pu.w2[0];
                    pb[fi][cj][1] = pu.w2[1];
                }
            }

            #pragma unroll
            for (int fi = 0; fi < 2; fi++)
                #pragma unroll
                for (int cjd = 0; cjd < 4; cjd++)
                    #pragma unroll
                    for (int j = 0; j < 4; j++) o[fi][cjd][j] *= fac[fi];

            // PV: O^T += V^T P^T (P^T B-fragment via 8 shfl + 4 select)
            const int srcA = l15 + ((lane >> 4) & 1) * 32;
            const int srcB = srcA + 16;
            const bool hicj = (lane >= 32);
            #pragma unroll
            for (int kkc = 0; kkc < 2; kkc++) {
                bf16x8 pf_[2];
                #pragma unroll
                for (int fi = 0; fi < 2; fi++) {
                    u32 a00 = (u32)__shfl((int)pb[fi][2 * kkc + 0][0], srcA);
                    u32 a01 = (u32)__shfl((int)pb[fi][2 * kkc + 0][1], srcA);
                    u32 a10 = (u32)__shfl((int)pb[fi][2 * kkc + 1][0], srcA);
                    u32 a11 = (u32)__shfl((int)pb[fi][2 * kkc + 1][1], srcA);
                    u32 b00 = (u32)__shfl((int)pb[fi][2 * kkc + 0][0], srcB);
                    u32 b01 = (u32)__shfl((int)pb[fi][2 * kkc + 0][1], srcB);
                    u32 b10 = (u32)__shfl((int)pb[fi][2 * kkc + 1][0], srcB);
                    u32 b11 = (u32)__shfl((int)pb[fi][2 * kkc + 1][1], srcB);
                    union { u32 w4[4]; bf16x8 v; } uu;
                    uu.w4[0] = hicj ? a10 : a00;
                    uu.w4[1] = hicj ? a11 : a01;
                    uu.w4[2] = hicj ? b10 : b00;
                    uu.w4[3] = hicj ? b11 : b01;
                    pf_[fi] = uu.v;
                }
                #pragma unroll
                for (int cjd = 0; cjd < 4; cjd++)
                    #pragma unroll
                    for (int fi = 0; fi < 2; fi++)
                        o[fi][cjd] = __builtin_amdgcn_mfma_f32_16x16x32_bf16(vf[cjd][kkc], pf_[fi], o[fi][cjd], 0, 0, 0);
            }
        }

        // ---- combine 16 -> 1 through 4 LDS slots ----
        // half-step A1: waves 8-11 publish, waves 0-3 merge
        if (w >= 8 && w < 12) WRITE_SLOT(w - 8);
        __syncthreads();
        if (w < 4) MERGE_SLOT(w);
        __syncthreads();
        // half-step A2: waves 12-15 publish, waves 4-7 merge
        if (w >= 12) WRITE_SLOT(w - 12);
        __syncthreads();
        if (w >= 4 && w < 8) MERGE_SLOT(w - 4);
        __syncthreads();
        // tree r=4
        if (w >= 4 && w < 8) WRITE_SLOT(w - 4);
        __syncthreads();
        if (w < 4) MERGE_SLOT(w);
        __syncthreads();
        // tree r=2
        if (w >= 2 && w < 4) WRITE_SLOT(w - 2);
        __syncthreads();
        if (w < 2) MERGE_SLOT(w);
        __syncthreads();
        // tree r=1
        if (w == 1) WRITE_SLOT(0);
        __syncthreads();
        if (w == 0) {
            MERGE_SLOT(0);
            float* ob = out + ((size_t)b * SS + q0) * DH;
            #pragma unroll
            for (int fi = 0; fi < 2; fi++) {
                float rl = 1.0f / l_[fi];
                #pragma unroll
                for (int cjd = 0; cjd < 4; cjd++) {
                    f32x4 v = o[fi][cjd] * rl;
                    *reinterpret_cast<f32x4*>(&ob[(size_t)(fi * 16 + l15) * DH + cjd * 16 + g * 4]) = v;
                }
            }
        }
        __syncthreads();   // slots reused by next phase
    }
    #undef WRITE_SLOT
    #undef MERGE_SLOT
}

// ---------------------------------------------------------------------------
extern "C" void kernel_launch(void* const* d_in, const int* in_sizes, int n_in,
                              void* d_out, int out_size, void* d_ws, size_t ws_size,
                              hipStream_t stream) {
    const float* x  = (const float*)d_in[0];
    const float* wq = (const float*)d_in[1];
    const float* wk = (const float*)d_in[2];
    const float* wv = (const float*)d_in[3];
    float* out = (float*)d_out;

    char* ws = (char*)d_ws;
    bf16_t* Qw = (bf16_t*)(ws + QOFF);
    bf16_t* Kw = (bf16_t*)(ws + KOFF);
    bf16_t* Vt = (bf16_t*)(ws + VOFF);
    bf16_t* Wt = (bf16_t*)(ws + WOFF);

    hipLaunchKernelGGL(wt_kernel, dim3((3 * DM * DH + 255) / 256), dim3(256), 0, stream,
                       wq, wk, wv, Wt);
    hipLaunchKernelGGL(proj_kernel, dim3(NROW / 32), dim3(256), 0, stream,
                       x, Wt, Qw, Kw, Vt);
    hipLaunchKernelGGL(attn_kernel, dim3(NB * 64), dim3(1024), 0, stream,
                       Qw, Kw, Vt, out);
}

// Round 6
// 108.995 us; speedup vs baseline: 1.4557x; 1.0156x over previous
//
#include <hip/hip_runtime.h>
#include <hip/hip_bf16.h>

typedef __bf16 bf16_t;
typedef bf16_t bf16x8 __attribute__((ext_vector_type(8)));
typedef float f32x4 __attribute__((ext_vector_type(4)));
typedef float f32x16 __attribute__((ext_vector_type(16)));
typedef unsigned int u32;

#define NB 4
#define SS 4096
#define DM 768
#define DH 64
#define NROW (NB * SS)   // 16384
#define CSCALE (0.125f * 1.44269504088896341f)   // 1/sqrt(64) * log2(e)
#define MFIX 24.0f       // fixed softmax max (scores ~N(0,1)*log2e, |s|max ~ 8)

// ws byte offsets
#define QOFF 0u
#define KOFF 2097152u
#define VOFF 4194304u
#define WOFF 6291456u

__device__ __forceinline__ u32 cvtpk_bf16(float lo, float hi) {
    u32 r;
    asm volatile("v_cvt_pk_bf16_f32 %0, %1, %2" : "=v"(r) : "v"(lo), "v"(hi));
    return r;
}

// ---------------------------------------------------------------------------
// Kernel 1: transpose W_{Q,K,V} [768][64] fp32 -> Wt[3][64][768] bf16
// ---------------------------------------------------------------------------
__global__ __launch_bounds__(256) void wt_kernel(const float* __restrict__ wq,
                                                 const float* __restrict__ wk,
                                                 const float* __restrict__ wv,
                                                 bf16_t* __restrict__ wt) {
    int id = blockIdx.x * 256 + threadIdx.x;
    if (id >= 3 * DM * DH) return;
    int m = id / (DM * DH);
    int r = id - m * (DM * DH);
    int k = r >> 6;
    int c = r & 63;
    const float* w = (m == 0) ? wq : (m == 1) ? wk : wv;
    wt[(size_t)m * DH * DM + (size_t)c * DM + k] = (bf16_t)w[k * DH + c];
}

// ---------------------------------------------------------------------------
// Kernel 2: projections. 512 blocks x 8 waves; wave = 16 rows x 48 cols.
// 4096 waves = 16/CU. x prefetched 2 steps ahead, Wt 1 step ahead.
// ---------------------------------------------------------------------------
__global__ __launch_bounds__(512, 4) void proj_kernel(const float* __restrict__ x,
                                                      const bf16_t* __restrict__ wt,
                                                      bf16_t* __restrict__ Qo,
                                                      bf16_t* __restrict__ Ko,
                                                      bf16_t* __restrict__ Vt) {
    const int lane = threadIdx.x & 63;
    const int wid = threadIdx.x >> 6;    // 0..7
    const int wr = wid & 1;
    const int wc = wid >> 1;             // 0..3
    const int l15 = lane & 15;
    const int g = lane >> 4;
    const int m0 = blockIdx.x * 32 + wr * 16;

    f32x4 acc[3];
    #pragma unroll
    for (int n = 0; n < 3; n++)
        #pragma unroll
        for (int j = 0; j < 4; j++) acc[n][j] = 0.0f;

    const float* xb = x + (size_t)(m0 + l15) * DM + g * 8;

    size_t wbase[3];
    #pragma unroll
    for (int n = 0; n < 3; n++) {
        const int gn = wc * 3 + n;
        const int mm = gn >> 2;
        const int cj = gn & 3;
        wbase[n] = (size_t)mm * DH * DM + (size_t)(cj * 16 + l15) * DM + g * 8;
    }

    f32x4 pf[2][2][2];   // [slot][kk][half]
    #pragma unroll
    for (int s = 0; s < 2; s++)
        #pragma unroll
        for (int kk = 0; kk < 2; kk++)
            #pragma unroll
            for (int h = 0; h < 2; h++)
                pf[s][kk][h] = *reinterpret_cast<const f32x4*>(xb + s * 64 + kk * 32 + h * 4);

    bf16x8 bb[2][3][2];
    #pragma unroll
    for (int n = 0; n < 3; n++)
        #pragma unroll
        for (int kk = 0; kk < 2; kk++)
            bb[0][n][kk] = *reinterpret_cast<const bf16x8*>(wt + wbase[n] + kk * 32);

    #pragma unroll
    for (int k = 0; k < 12; k++) {
        const int cur = k & 1;
        const int nxt = (k + 1) & 1;
        bf16x8 a[2];
        #pragma unroll
        for (int kk = 0; kk < 2; kk++) {
            bf16x8 t;
            #pragma unroll
            for (int j = 0; j < 4; j++) {
                t[j] = (bf16_t)pf[cur][kk][0][j];
                t[4 + j] = (bf16_t)pf[cur][kk][1][j];
            }
            a[kk] = t;
        }
        if (k + 2 < 12) {
            #pragma unroll
            for (int kk = 0; kk < 2; kk++)
                #pragma unroll
                for (int h = 0; h < 2; h++)
                    pf[cur][kk][h] = *reinterpret_cast<const f32x4*>(
                        xb + (k + 2) * 64 + kk * 32 + h * 4);
        }
        if (k + 1 < 12) {
            #pragma unroll
            for (int n = 0; n < 3; n++)
                #pragma unroll
                for (int kk = 0; kk < 2; kk++)
                    bb[nxt][n][kk] = *reinterpret_cast<const bf16x8*>(
                        wt + wbase[n] + (k + 1) * 64 + kk * 32);
        }
        #pragma unroll
        for (int n = 0; n < 3; n++)
            #pragma unroll
            for (int kk = 0; kk < 2; kk++)
                acc[n] = __builtin_amdgcn_mfma_f32_16x16x32_bf16(a[kk], bb[cur][n][kk], acc[n], 0, 0, 0);
    }

    #pragma unroll
    for (int n = 0; n < 3; n++) {
        const int gn = wc * 3 + n;
        const int mm = gn >> 2;
        const int cj = gn & 3;
        #pragma unroll
        for (int j = 0; j < 4; j++) {
            int row = m0 + g * 4 + j;
            int col = cj * 16 + l15;
            float v = acc[n][j];
            if (mm == 0)      Qo[(size_t)row * DH + col] = (bf16_t)(v * CSCALE);
            else if (mm == 1) Ko[(size_t)row * DH + col] = (bf16_t)v;
            else              Vt[(size_t)col * NROW + row] = (bf16_t)v;
        }
    }
}

// ---------------------------------------------------------------------------
// Kernel 3: flash attention, 32x32 MFMA + fixed-max softmax. 256 uniform
// blocks x 16 waves; block = tile pair (64+pr, 63-pr). Swapped QK^T
// (A=K, B=Q): lane l31 owns q; p = exp2(s - 24) needs NO row reduce (scores
// ~N(0,1): max << 24, overflow impossible). P C-layout -> PV A-operand via
// 16 cvt_pk + 8 permlane32_swap per 64-kv tile -- zero DS ops in the loop.
// l is a per-lane partial, reduced once at the end. Combine = plain adds.
// ---------------------------------------------------------------------------
__global__ __launch_bounds__(1024, 4) void attn_kernel(const bf16_t* __restrict__ Q,
                                                       const bf16_t* __restrict__ K,
                                                       const bf16_t* __restrict__ Vt,
                                                       float* __restrict__ out) {
    __shared__ float Ob[4][2][16][64];   // [slot][c][reg][lane] - lane-coalesced
    __shared__ float Ls[4][64];

    const int tid = threadIdx.x;
    const int lane = tid & 63;
    const int w = tid >> 6;              // 0..15
    const int l31 = lane & 31;
    const int hi = lane >> 5;
    const int bx = blockIdx.x;           // 0..255
    const int b = (bx & 7) >> 1;         // batch pinned to 2 XCDs
    const int pr = (bx >> 3) * 2 + (bx & 1);   // 0..63

    const bf16_t* Qb = Q + (size_t)b * SS * DH;
    const bf16_t* Kb = K + (size_t)b * SS * DH;
    const bf16_t* Vb = Vt + (size_t)b * SS;

    #pragma unroll
    for (int ph = 0; ph < 2; ph++) {
        const int tile = (ph == 0) ? (64 + pr) : (63 - pr);
        const int q0 = tile * 32;
        const int nkv = (tile >> 1) + 1;
        const int q = q0 + l31;

        // Q B-fragments, hoisted: B[k=d][col=q], d = ks*16 + hi*8 + e
        bf16x8 bq[4];
        #pragma unroll
        for (int ks = 0; ks < 4; ks++)
            bq[ks] = *reinterpret_cast<const bf16x8*>(
                Qb + (size_t)(q0 + l31) * DH + ks * 16 + hi * 8);

        f32x16 o[2];
        #pragma unroll
        for (int c = 0; c < 2; c++)
            #pragma unroll
            for (int r = 0; r < 16; r++) o[c][r] = 0.0f;
        float lsum = 0.0f;

        for (int kt = w; kt < nkv; kt += 16) {
            const int kv0 = kt * 64;
            const bool diag = (kv0 + 63 > q0);

            // V B-fragments for the whole 64-kv tile (issued early)
            bf16x8 vf[2][4];   // [c][kks]
            #pragma unroll
            for (int c = 0; c < 2; c++)
                #pragma unroll
                for (int kks = 0; kks < 4; kks++)
                    vf[c][kks] = *reinterpret_cast<const bf16x8*>(
                        Vb + (size_t)(c * 32 + l31) * NROW + kv0 + kks * 16 + hi * 8);

            u32 pa[4][4];   // [kstep][word] PV A-fragments
            #pragma unroll
            for (int blk = 0; blk < 2; blk++) {
                // K A-fragments: A[row=kv][k=d]
                bf16x8 ak[4];
                #pragma unroll
                for (int ks = 0; ks < 4; ks++)
                    ak[ks] = *reinterpret_cast<const bf16x8*>(
                        Kb + (size_t)(kv0 + blk * 32 + l31) * DH + ks * 16 + hi * 8);

                // S^T[kv][q] 32x32
                f32x16 s;
                #pragma unroll
                for (int r = 0; r < 16; r++) s[r] = 0.0f;
                #pragma unroll
                for (int ks = 0; ks < 4; ks++)
                    s = __builtin_amdgcn_mfma_f32_32x32x16_bf16(ak[ks], bq[ks], s, 0, 0, 0);

                // fixed-max softmax + causal mask (all in-lane)
                const int kvbase = kv0 + blk * 32 + 4 * hi;
                float p[16];
                #pragma unroll
                for (int r = 0; r < 16; r++) {
                    float e = exp2f(s[r] - MFIX);
                    if (diag) {
                        int kv = kvbase + (r & 3) + 8 * (r >> 2);
                        e = (kv > q) ? 0.0f : e;
                    }
                    p[r] = e;
                    lsum += e;
                }

                // pack to bf16 + permlane32_swap -> A-operand fragments
                #pragma unroll
                for (int ks2 = 0; ks2 < 2; ks2++) {
                    u32 w01 = cvtpk_bf16(p[8 * ks2 + 0], p[8 * ks2 + 1]);
                    u32 w23 = cvtpk_bf16(p[8 * ks2 + 2], p[8 * ks2 + 3]);
                    u32 w45 = cvtpk_bf16(p[8 * ks2 + 4], p[8 * ks2 + 5]);
                    u32 w67 = cvtpk_bf16(p[8 * ks2 + 6], p[8 * ks2 + 7]);
                    // after swap: w01={w0 lo-half, kv(8,9) hi-half}, w45={kv(4,5) lo, w2 hi}
                    asm volatile("v_permlane32_swap_b32 %0, %1" : "+v"(w01), "+v"(w45));
                    asm volatile("v_permlane32_swap_b32 %0, %1" : "+v"(w23), "+v"(w67));
                    pa[blk * 2 + ks2][0] = w01;
                    pa[blk * 2 + ks2][1] = w23;
                    pa[blk * 2 + ks2][2] = w45;
                    pa[blk * 2 + ks2][3] = w67;
                }
            }

            // PV: O[q][d] += P[q][kv] * V[kv][d]
            #pragma unroll
            for (int kks = 0; kks < 4; kks++) {
                union { u32 w4[4]; bf16x8 v; } uu;
                uu.w4[0] = pa[kks][0];
                uu.w4[1] = pa[kks][1];
                uu.w4[2] = pa[kks][2];
                uu.w4[3] = pa[kks][3];
                #pragma unroll
                for (int c = 0; c < 2; c++)
                    o[c] = __builtin_amdgcn_mfma_f32_32x32x16_bf16(uu.v, vf[c][kks], o[c], 0, 0, 0);
            }
        }

        // ---- combine 16 -> 1 (plain adds: fixed max, empty waves add 0) ----
        #define WRITE_SLOT(s_)                                                      \
            {                                                                       \
                _Pragma("unroll")                                                   \
                for (int c = 0; c < 2; c++)                                         \
                    _Pragma("unroll")                                               \
                    for (int r = 0; r < 16; r++) Ob[s_][c][r][lane] = o[c][r];      \
                Ls[s_][lane] = lsum;                                                \
            }
        #define MERGE_SLOT(s_)                                                      \
            {                                                                       \
                _Pragma("unroll")                                                   \
                for (int c = 0; c < 2; c++)                                         \
                    _Pragma("unroll")                                               \
                    for (int r = 0; r < 16; r++) o[c][r] += Ob[s_][c][r][lane];     \
                lsum += Ls[s_][lane];                                               \
            }

        if (w >= 8 && w < 12) WRITE_SLOT(w - 8);
        __syncthreads();
        if (w < 4) MERGE_SLOT(w);
        __syncthreads();
        if (w >= 12) WRITE_SLOT(w - 12);
        __syncthreads();
        if (w >= 4 && w < 8) MERGE_SLOT(w - 4);
        __syncthreads();
        if (w >= 4 && w < 8) WRITE_SLOT(w - 4);
        __syncthreads();
        if (w < 4) MERGE_SLOT(w);
        __syncthreads();
        if (w >= 2 && w < 4) WRITE_SLOT(w - 2);
        __syncthreads();
        if (w < 2) MERGE_SLOT(w);
        __syncthreads();
        if (w == 1) WRITE_SLOT(0);
        __syncthreads();
        if (w == 0) {
            MERGE_SLOT(0);
            float lfull = lsum + __shfl_xor(lsum, 32);
            float* ob = out + ((size_t)b * SS + q0) * DH;
            #pragma unroll
            for (int c = 0; c < 2; c++)
                #pragma unroll
                for (int r = 0; r < 16; r++) {
                    const int qr = (r & 3) + 8 * (r >> 2) + 4 * hi;
                    float lr = __shfl(lfull, qr);
                    ob[(size_t)qr * DH + c * 32 + l31] = o[c][r] / lr;
                }
        }
        __syncthreads();   // slots reused by next phase
        #undef WRITE_SLOT
        #undef MERGE_SLOT
    }
}

// ---------------------------------------------------------------------------
extern "C" void kernel_launch(void* const* d_in, const int* in_sizes, int n_in,
                              void* d_out, int out_size, void* d_ws, size_t ws_size,
                              hipStream_t stream) {
    const float* x  = (const float*)d_in[0];
    const float* wq = (const float*)d_in[1];
    const float* wk = (const float*)d_in[2];
    const float* wv = (const float*)d_in[3];
    float* out = (float*)d_out;

    char* ws = (char*)d_ws;
    bf16_t* Qw = (bf16_t*)(ws + QOFF);
    bf16_t* Kw = (bf16_t*)(ws + KOFF);
    bf16_t* Vt = (bf16_t*)(ws + VOFF);
    bf16_t* Wt = (bf16_t*)(ws + WOFF);

    hipLaunchKernelGGL(wt_kernel, dim3((3 * DM * DH + 255) / 256), dim3(256), 0, stream,
                       wq, wk, wv, Wt);
    hipLaunchKernelGGL(proj_kernel, dim3(NROW / 32), dim3(512), 0, stream,
                       x, Wt, Qw, Kw, Vt);
    hipLaunchKernelGGL(attn_kernel, dim3(NB * 64), dim3(1024), 0, stream,
                       Qw, Kw, Vt, out);
}

// Round 7
// 91.711 us; speedup vs baseline: 1.7300x; 1.1885x over previous
//
#include <hip/hip_runtime.h>
#include <hip/hip_bf16.h>

typedef __bf16 bf16_t;
typedef bf16_t bf16x8 __attribute__((ext_vector_type(8)));
typedef float f32x4 __attribute__((ext_vector_type(4)));
typedef float f32x16 __attribute__((ext_vector_type(16)));
typedef unsigned int u32;

#define NB 4
#define SS 4096
#define DM 768
#define DH 64
#define NROW (NB * SS)   // 16384
#define CSCALE (0.125f * 1.44269504088896341f)   // 1/sqrt(64) * log2(e)
#define MFIX 24.0f       // fixed softmax max (scores ~N(0,1)*log2e, |s|max ~ 8)

// ws byte offsets
#define QOFF 0u
#define KOFF 2097152u
#define VOFF 4194304u
#define WOFF 6291456u

__device__ __forceinline__ u32 cvtpk_bf16(float lo, float hi) {
    u32 r;
    asm volatile("v_cvt_pk_bf16_f32 %0, %1, %2" : "=v"(r) : "v"(lo), "v"(hi));
    return r;
}

// ---------------------------------------------------------------------------
// Kernel 1: transpose W_{Q,K,V} [768][64] fp32 -> Wt[3][64][768] bf16
// ---------------------------------------------------------------------------
__global__ __launch_bounds__(256) void wt_kernel(const float* __restrict__ wq,
                                                 const float* __restrict__ wk,
                                                 const float* __restrict__ wv,
                                                 bf16_t* __restrict__ wt) {
    int id = blockIdx.x * 256 + threadIdx.x;
    if (id >= 3 * DM * DH) return;
    int m = id / (DM * DH);
    int r = id - m * (DM * DH);
    int k = r >> 6;
    int c = r & 63;
    const float* w = (m == 0) ? wq : (m == 1) ? wk : wv;
    wt[(size_t)m * DH * DM + (size_t)c * DM + k] = (bf16_t)w[k * DH + c];
}

// ---------------------------------------------------------------------------
// Kernel 2: projections, global_load_lds staged (T3 minimum 2-phase).
// 512 blocks x 8 waves; BM=32 rows, BK=64. Per k-step: each thread issues ONE
// global_load_lds (16B) staging the 32x64 fp32 x-tile into the next LDS buf;
// A-frags read from current buf (XOR-swizzled source+read: conflict-free);
// Wt fragments prefetched into regs one step ahead (issued pre-barrier =>
// sink-proof). __syncthreads' vmcnt drain is the pipeline wait.
// Wave (wr=wid&1, wc=wid>>1): rows wr*16+16, cols wc*48+48.
// ---------------------------------------------------------------------------
__global__ __launch_bounds__(512, 4) void proj_kernel(const float* __restrict__ x,
                                                      const bf16_t* __restrict__ wt,
                                                      bf16_t* __restrict__ Qo,
                                                      bf16_t* __restrict__ Ko,
                                                      bf16_t* __restrict__ Vt) {
    __shared__ __align__(16) float xs[2][2048];   // 2 x 32 rows x 64 k fp32 = 16 KB

    const int tid = threadIdx.x;
    const int lane = tid & 63;
    const int wid = tid >> 6;            // 0..7
    const int wr = wid & 1;
    const int wc = wid >> 1;             // 0..3
    const int l15 = lane & 15;
    const int g = lane >> 4;
    const int m0 = blockIdx.x * 32;

    // staging source: thread t covers (row = t>>4, chunk kc_src = (t&15)^(row&7))
    // so that LINEAR LDS slot t holds global chunk (row, (t&15)^(row&7)) --
    // reader XORs the same way => conflict-free ds_read_b128 (T2/m173 pattern).
    const int srow = tid >> 4;
    const int skc = (tid & 15) ^ (srow & 7);
    const float* sbase = x + (size_t)(m0 + srow) * DM + skc * 4;

    #define STAGE(bsel, t_)                                                         \
        __builtin_amdgcn_global_load_lds(                                           \
            (const __attribute__((address_space(1))) void*)(sbase + (t_) * 64),     \
            (__attribute__((address_space(3))) void*)(&xs[bsel][wid * 256]),        \
            16, 0, 0);

    size_t wbase[3];
    #pragma unroll
    for (int n = 0; n < 3; n++) {
        const int gn = wc * 3 + n;
        const int mm = gn >> 2;
        const int cj = gn & 3;
        wbase[n] = (size_t)mm * DH * DM + (size_t)(cj * 16 + l15) * DM + g * 8;
    }

    f32x4 acc[3];
    #pragma unroll
    for (int n = 0; n < 3; n++)
        #pragma unroll
        for (int j = 0; j < 4; j++) acc[n][j] = 0.0f;

    // reader offsets (fp32 elements) for A-frag chunks: row, kc = kk*8+g*2+c
    const int arow = wr * 16 + l15;
    int roff[2][2];
    #pragma unroll
    for (int kk = 0; kk < 2; kk++)
        #pragma unroll
        for (int c = 0; c < 2; c++)
            roff[kk][c] = arow * 64 + ((kk * 8 + g * 2 + c) ^ (arow & 7)) * 4;

    // prologue: stage tile 0, prefetch Wt tile 0
    STAGE(0, 0);
    bf16x8 wcur[3][2], wnext[3][2];
    #pragma unroll
    for (int n = 0; n < 3; n++)
        #pragma unroll
        for (int kk = 0; kk < 2; kk++)
            wcur[n][kk] = *reinterpret_cast<const bf16x8*>(wt + wbase[n] + kk * 32);
    __syncthreads();

    #pragma unroll
    for (int t = 0; t < 12; t++) {
        const int cur = t & 1;
        // issue next tile's staging + Wt prefetch FIRST (pre-barrier => pinned)
        if (t < 11) {
            STAGE(cur ^ 1, t + 1);
            #pragma unroll
            for (int n = 0; n < 3; n++)
                #pragma unroll
                for (int kk = 0; kk < 2; kk++)
                    wnext[n][kk] = *reinterpret_cast<const bf16x8*>(
                        wt + wbase[n] + (t + 1) * 64 + kk * 32);
        }
        // A fragments from LDS (swizzled), fp32 -> bf16
        bf16x8 a[2];
        #pragma unroll
        for (int kk = 0; kk < 2; kk++) {
            f32x4 c0 = *reinterpret_cast<const f32x4*>(&xs[cur][roff[kk][0]]);
            f32x4 c1 = *reinterpret_cast<const f32x4*>(&xs[cur][roff[kk][1]]);
            bf16x8 tt;
            #pragma unroll
            for (int j = 0; j < 4; j++) { tt[j] = (bf16_t)c0[j]; tt[4 + j] = (bf16_t)c1[j]; }
            a[kk] = tt;
        }
        #pragma unroll
        for (int n = 0; n < 3; n++)
            #pragma unroll
            for (int kk = 0; kk < 2; kk++)
                acc[n] = __builtin_amdgcn_mfma_f32_16x16x32_bf16(a[kk], wcur[n][kk], acc[n], 0, 0, 0);

        if (t < 11) {
            __syncthreads();   // drains vmcnt: stage t+1 + wnext landed
            #pragma unroll
            for (int n = 0; n < 3; n++)
                #pragma unroll
                for (int kk = 0; kk < 2; kk++)
                    wcur[n][kk] = wnext[n][kk];
        }
    }
    #undef STAGE

    #pragma unroll
    for (int n = 0; n < 3; n++) {
        const int gn = wc * 3 + n;
        const int mm = gn >> 2;
        const int cj = gn & 3;
        #pragma unroll
        for (int j = 0; j < 4; j++) {
            int row = m0 + wr * 16 + g * 4 + j;
            int col = cj * 16 + l15;
            float v = acc[n][j];
            if (mm == 0)      Qo[(size_t)row * DH + col] = (bf16_t)(v * CSCALE);
            else if (mm == 1) Ko[(size_t)row * DH + col] = (bf16_t)v;
            else              Vt[(size_t)col * NROW + row] = (bf16_t)v;
        }
    }
}

// ---------------------------------------------------------------------------
// Kernel 3: flash attention, 32x32 MFMA + fixed-max softmax (unchanged R5).
// ---------------------------------------------------------------------------
__global__ __launch_bounds__(1024, 4) void attn_kernel(const bf16_t* __restrict__ Q,
                                                       const bf16_t* __restrict__ K,
                                                       const bf16_t* __restrict__ Vt,
                                                       float* __restrict__ out) {
    __shared__ float Ob[4][2][16][64];   // [slot][c][reg][lane]
    __shared__ float Ls[4][64];

    const int tid = threadIdx.x;
    const int lane = tid & 63;
    const int w = tid >> 6;              // 0..15
    const int l31 = lane & 31;
    const int hi = lane >> 5;
    const int bx = blockIdx.x;           // 0..255
    const int b = (bx & 7) >> 1;         // batch pinned to 2 XCDs
    const int pr = (bx >> 3) * 2 + (bx & 1);   // 0..63

    const bf16_t* Qb = Q + (size_t)b * SS * DH;
    const bf16_t* Kb = K + (size_t)b * SS * DH;
    const bf16_t* Vb = Vt + (size_t)b * SS;

    #pragma unroll
    for (int ph = 0; ph < 2; ph++) {
        const int tile = (ph == 0) ? (64 + pr) : (63 - pr);
        const int q0 = tile * 32;
        const int nkv = (tile >> 1) + 1;
        const int q = q0 + l31;

        bf16x8 bq[4];
        #pragma unroll
        for (int ks = 0; ks < 4; ks++)
            bq[ks] = *reinterpret_cast<const bf16x8*>(
                Qb + (size_t)(q0 + l31) * DH + ks * 16 + hi * 8);

        f32x16 o[2];
        #pragma unroll
        for (int c = 0; c < 2; c++)
            #pragma unroll
            for (int r = 0; r < 16; r++) o[c][r] = 0.0f;
        float lsum = 0.0f;

        for (int kt = w; kt < nkv; kt += 16) {
            const int kv0 = kt * 64;
            const bool diag = (kv0 + 63 > q0);

            bf16x8 vf[2][4];
            #pragma unroll
            for (int c = 0; c < 2; c++)
                #pragma unroll
                for (int kks = 0; kks < 4; kks++)
                    vf[c][kks] = *reinterpret_cast<const bf16x8*>(
                        Vb + (size_t)(c * 32 + l31) * NROW + kv0 + kks * 16 + hi * 8);

            u32 pa[4][4];
            #pragma unroll
            for (int blk = 0; blk < 2; blk++) {
                bf16x8 ak[4];
                #pragma unroll
                for (int ks = 0; ks < 4; ks++)
                    ak[ks] = *reinterpret_cast<const bf16x8*>(
                        Kb + (size_t)(kv0 + blk * 32 + l31) * DH + ks * 16 + hi * 8);

                f32x16 s;
                #pragma unroll
                for (int r = 0; r < 16; r++) s[r] = 0.0f;
                #pragma unroll
                for (int ks = 0; ks < 4; ks++)
                    s = __builtin_amdgcn_mfma_f32_32x32x16_bf16(ak[ks], bq[ks], s, 0, 0, 0);

                const int kvbase = kv0 + blk * 32 + 4 * hi;
                float p[16];
                #pragma unroll
                for (int r = 0; r < 16; r++) {
                    float e = exp2f(s[r] - MFIX);
                    if (diag) {
                        int kv = kvbase + (r & 3) + 8 * (r >> 2);
                        e = (kv > q) ? 0.0f : e;
                    }
                    p[r] = e;
                    lsum += e;
                }

                #pragma unroll
                for (int ks2 = 0; ks2 < 2; ks2++) {
                    u32 w01 = cvtpk_bf16(p[8 * ks2 + 0], p[8 * ks2 + 1]);
                    u32 w23 = cvtpk_bf16(p[8 * ks2 + 2], p[8 * ks2 + 3]);
                    u32 w45 = cvtpk_bf16(p[8 * ks2 + 4], p[8 * ks2 + 5]);
                    u32 w67 = cvtpk_bf16(p[8 * ks2 + 6], p[8 * ks2 + 7]);
                    asm volatile("v_permlane32_swap_b32 %0, %1" : "+v"(w01), "+v"(w45));
                    asm volatile("v_permlane32_swap_b32 %0, %1" : "+v"(w23), "+v"(w67));
                    pa[blk * 2 + ks2][0] = w01;
                    pa[blk * 2 + ks2][1] = w23;
                    pa[blk * 2 + ks2][2] = w45;
                    pa[blk * 2 + ks2][3] = w67;
                }
            }

            #pragma unroll
            for (int kks = 0; kks < 4; kks++) {
                union { u32 w4[4]; bf16x8 v; } uu;
                uu.w4[0] = pa[kks][0];
                uu.w4[1] = pa[kks][1];
                uu.w4[2] = pa[kks][2];
                uu.w4[3] = pa[kks][3];
                #pragma unroll
                for (int c = 0; c < 2; c++)
                    o[c] = __builtin_amdgcn_mfma_f32_32x32x16_bf16(uu.v, vf[c][kks], o[c], 0, 0, 0);
            }
        }

        #define WRITE_SLOT(s_)                                                      \
            {                                                                       \
                _Pragma("unroll")                                                   \
                for (int c = 0; c < 2; c++)                                         \
                    _Pragma("unroll")                                               \
                    for (int r = 0; r < 16; r++) Ob[s_][c][r][lane] = o[c][r];      \
                Ls[s_][lane] = lsum;                                                \
            }
        #define MERGE_SLOT(s_)                                                      \
            {                                                                       \
                _Pragma("unroll")                                                   \
                for (int c = 0; c < 2; c++)                                         \
                    _Pragma("unroll")                                               \
                    for (int r = 0; r < 16; r++) o[c][r] += Ob[s_][c][r][lane];     \
                lsum += Ls[s_][lane];                                               \
            }

        if (w >= 8 && w < 12) WRITE_SLOT(w - 8);
        __syncthreads();
        if (w < 4) MERGE_SLOT(w);
        __syncthreads();
        if (w >= 12) WRITE_SLOT(w - 12);
        __syncthreads();
        if (w >= 4 && w < 8) MERGE_SLOT(w - 4);
        __syncthreads();
        if (w >= 4 && w < 8) WRITE_SLOT(w - 4);
        __syncthreads();
        if (w < 4) MERGE_SLOT(w);
        __syncthreads();
        if (w >= 2 && w < 4) WRITE_SLOT(w - 2);
        __syncthreads();
        if (w < 2) MERGE_SLOT(w);
        __syncthreads();
        if (w == 1) WRITE_SLOT(0);
        __syncthreads();
        if (w == 0) {
            MERGE_SLOT(0);
            float lfull = lsum + __shfl_xor(lsum, 32);
            float* ob = out + ((size_t)b * SS + q0) * DH;
            #pragma unroll
            for (int c = 0; c < 2; c++)
                #pragma unroll
                for (int r = 0; r < 16; r++) {
                    const int qr = (r & 3) + 8 * (r >> 2) + 4 * hi;
                    float lr = __shfl(lfull, qr);
                    ob[(size_t)qr * DH + c * 32 + l31] = o[c][r] / lr;
                }
        }
        __syncthreads();
        #undef WRITE_SLOT
        #undef MERGE_SLOT
    }
}

// ---------------------------------------------------------------------------
extern "C" void kernel_launch(void* const* d_in, const int* in_sizes, int n_in,
                              void* d_out, int out_size, void* d_ws, size_t ws_size,
                              hipStream_t stream) {
    const float* x  = (const float*)d_in[0];
    const float* wq = (const float*)d_in[1];
    const float* wk = (const float*)d_in[2];
    const float* wv = (const float*)d_in[3];
    float* out = (float*)d_out;

    char* ws = (char*)d_ws;
    bf16_t* Qw = (bf16_t*)(ws + QOFF);
    bf16_t* Kw = (bf16_t*)(ws + KOFF);
    bf16_t* Vt = (bf16_t*)(ws + VOFF);
    bf16_t* Wt = (bf16_t*)(ws + WOFF);

    hipLaunchKernelGGL(wt_kernel, dim3((3 * DM * DH + 255) / 256), dim3(256), 0, stream,
                       wq, wk, wv, Wt);
    hipLaunchKernelGGL(proj_kernel, dim3(NROW / 32), dim3(512), 0, stream,
                       x, Wt, Qw, Kw, Vt);
    hipLaunchKernelGGL(attn_kernel, dim3(NB * 64), dim3(1024), 0, stream,
                       Qw, Kw, Vt, out);
}